// Round 9
// baseline (1605.819 us; speedup 1.0000x reference)
//
#include <hip/hip_runtime.h>
#include <hip/hip_bf16.h>

// Problem constants
#define BATCH 16384
#define SEW   2048      // SE == SO == 2048
#define H1W   1024
#define NSTEP 10

typedef unsigned short u16;
typedef __attribute__((ext_vector_type(8))) __bf16 bf16x8;
typedef __attribute__((ext_vector_type(4))) float   f32x4;

// Split fp32 into bf16 hi + bf16 lo (truncation; x == hi + lo + O(2^-16 |x|))
__device__ __forceinline__ void split2(float x, u16& h, u16& l) {
    unsigned u = __float_as_uint(x);
    h = (u16)(u >> 16);
    float hf = __uint_as_float(u & 0xFFFF0000u);
    float r  = x - hf;                       // exact (mantissa suffix)
    l = (u16)(__float_as_uint(r) >> 16);
}

__device__ __forceinline__ float rho_f(float x) {
    return 1.0f / (1.0f + __expf(2.0f - 4.0f * x));
}

// 16-byte async global->LDS copy
__device__ __forceinline__ void gl2lds16(const u16* g, u16* l) {
    __builtin_amdgcn_global_load_lds(
        (const __attribute__((address_space(1))) void*)g,
        (__attribute__((address_space(3))) void*)l, 16, 0, 0);
}

// ---------------------------------------------------------------------------
// prep_w: W (2048x2048 f32) -> Whi/Wlo and transposed WThi/WTlo (bf16 halves)
// ---------------------------------------------------------------------------
__global__ void prep_w(const float* __restrict__ W,
                       u16* __restrict__ Whi, u16* __restrict__ Wlo,
                       u16* __restrict__ WThi, u16* __restrict__ WTlo) {
    __shared__ float tile[32][33];
    const int tx = threadIdx.x, ty = threadIdx.y;
    const int x = blockIdx.x * 32 + tx;
#pragma unroll
    for (int k = 0; k < 4; ++k) {
        int y = blockIdx.y * 32 + ty + k * 8;
        float v = W[y * SEW + x];
        tile[ty + k * 8][tx] = v;
        u16 h, l; split2(v, h, l);
        Whi[y * SEW + x] = h; Wlo[y * SEW + x] = l;
    }
    __syncthreads();
#pragma unroll
    for (int k = 0; k < 4; ++k) {
        int r = blockIdx.x * 32 + ty + k * 8;   // WT row (= W col)
        int c = blockIdx.y * 32 + tx;           // WT col (= W row)
        float v = tile[tx][ty + k * 8];         // = W[c][r]
        u16 h, l; split2(v, h, l);
        WThi[r * SEW + c] = h; WTlo[r * SEW + c] = l;
    }
}

// ---------------------------------------------------------------------------
// prep_rho: R1 = rho(s_even) split to bf16 hi/lo.  s row stride 4096.
// ---------------------------------------------------------------------------
__global__ void prep_rho(const float* __restrict__ s,
                         u16* __restrict__ Rhi, u16* __restrict__ Rlo) {
    int i = blockIdx.x * blockDim.x + threadIdx.x;   // 0 .. B*SE/4-1
    int e = i << 2;
    int row = e >> 11;
    int col = e & 2047;
    const float4 v = *(const float4*)(s + ((size_t)row << 12) + col);
    float xs[4] = {v.x, v.y, v.z, v.w};
    u16 h[4], l[4];
#pragma unroll
    for (int k = 0; k < 4; ++k) {
        float r = rho_f(xs[k]);
        split2(r, h[k], l[k]);
    }
    *(ushort4*)(Rhi + e) = make_ushort4(h[0], h[1], h[2], h[3]);
    *(ushort4*)(Rlo + e) = make_ushort4(l[0], l[1], l[2], l[3]);
}

// ---------------------------------------------------------------------------
// Deep-pipelined split-bf16 GEMM.
//  BM=BN=256, BK=64, 512 threads = 8 waves (2Mx4N), 128x64 out per wave.
//  Virtual-K: per real 64-wide K-tile, 3 virtual tiles select sources
//    t=0: Ahi*Bhi   t=1: Ahi*Blo   t=2: Alo*Bhi   (sum = fp32-ish product)
//  Double-buffered 128KB LDS, counted s_waitcnt vmcnt(8) (never 0 in loop),
//  raw s_barrier (no drain), XOR-swizzled reads via pre-swizzled global src.
// ---------------------------------------------------------------------------
template <int PHASE>
__global__ __launch_bounds__(512, 2)
void gemm_fused(const u16* __restrict__ Ahi, const u16* __restrict__ Alo,
                const u16* __restrict__ Bhi, const u16* __restrict__ Blo,
                const float* __restrict__ bias,
                const float* __restrict__ Ux,
                const float* __restrict__ s_in,   // pre-offset, row stride 4096
                float* __restrict__ out,          // pre-offset, row stride 4096
                u16* __restrict__ R2hi, u16* __restrict__ R2lo) {
    __shared__ u16 ldsA[2][256 * 64];   // 2 x 32KB
    __shared__ u16 ldsB[2][256 * 64];   // 2 x 32KB

    const int tid = threadIdx.x;

    // ---- bijective XCD swizzle: 512 wgs, hw xcd = wgid & 7.
    // logical L: consecutive 64 L's (one m-panel x all 8 n + 7 more m-panels)
    // land on one XCD -> A m-panel (2MB) becomes L2-resident per XCD.
    const int wg = blockIdx.x;
    const int L  = (wg & 7) * 64 + (wg >> 3);
    const int m0 = (L >> 3) * 256;
    const int n0 = (L & 7) * 256;

    // ---- k range from block sparsity
    int kt0, nkt;
    if (PHASE == 1) { kt0 = 0;                    nkt = (n0 < 1024) ? 16 : 32; }
    else            { kt0 = (n0 < 1024) ? 0 : 16; nkt = (n0 < 1024) ? 32 : 16; }
    const int nvt = 3 * nkt;

    // ---- staging addresses: 2048 16B chunks/tile, 4 per thread.
    // chunk c = tid + 512*i: row = c>>3 = (tid>>3)+64i, slot = tid&7 (all i).
    // LDS dest linear (chunk*16B); global src column pre-swizzled by the
    // read-side XOR so read(rd-swz) o stage(src-swz) = identity.
    const int srow  = tid >> 3;
    const int sswz  = (tid >> 4) & 7;                 // ((row>>1)&7), same all i
    const int scol  = ((tid & 7) ^ sswz) * 8;         // element offset in 64-k row
    const int aoff0 = (m0 + srow) * SEW + scol;
    const int boff0 = (n0 + srow) * SEW + scol;

    // ---- fragment read offsets (bytes), swizzled
    const int lane = tid & 63;
    const int w  = tid >> 6;
    const int wr = w >> 2, wc = w & 3;                // 2M x 4N wave grid
    const int lr = lane & 15, q = lane >> 4;
    const int swz = (lr >> 1) & 7;
    const int oh0 = ((q)     ^ swz) * 16;             // k-half 0 slot
    const int oh1 = ((4 + q) ^ swz) * 16;             // k-half 1 slot
    const int baseA = (wr * 128 + lr) * 128;          // byte offset in A tile
    const int baseB = (wc * 64  + lr) * 128;          // byte offset in B tile

    f32x4 acc[8][4];
    const f32x4 zero = {0.f, 0.f, 0.f, 0.f};
#pragma unroll
    for (int i = 0; i < 8; ++i)
#pragma unroll
        for (int j = 0; j < 4; ++j) acc[i][j] = zero;

#define STAGE(As, Bs, kk, buf) do {                                          \
        u16* dA_ = &ldsA[buf][tid * 8];                                      \
        u16* dB_ = &ldsB[buf][tid * 8];                                      \
        const u16* sa_ = (As) + aoff0 + (kk);                                \
        const u16* sb_ = (Bs) + boff0 + (kk);                                \
        _Pragma("unroll")                                                    \
        for (int i_ = 0; i_ < 4; ++i_) {                                     \
            gl2lds16(sa_ + i_ * (64 * SEW), dA_ + i_ * 4096);                \
            gl2lds16(sb_ + i_ * (64 * SEW), dB_ + i_ * 4096);                \
        }                                                                    \
    } while (0)

    // prologue: stage vt=0 (t=0: Ahi*Bhi)
    int skk = kt0 * 64;
    int st  = 1;                 // next vt to stage has term t=1
    STAGE(Ahi, Bhi, skk, 0);

    for (int vt = 0; vt < nvt; ++vt) {
        const int cur = vt & 1;
        if (vt + 1 < nvt) {
            const u16* As = (st < 2)  ? Ahi : Alo;
            const u16* Bs = (st == 1) ? Blo : Bhi;
            STAGE(As, Bs, skk, cur ^ 1);
            if (++st == 3) { st = 0; skk += 64; }
            asm volatile("s_waitcnt vmcnt(8)" ::: "memory");  // tile vt done
        } else {
            asm volatile("s_waitcnt vmcnt(0)" ::: "memory");
        }
        __builtin_amdgcn_s_barrier();   // buf[cur] published to all waves

        const char* la = (const char*)ldsA[cur];
        const char* lb = (const char*)ldsB[cur];
        bf16x8 av[4][2], bv[4][2];
        // P1 reads: a rows i=0..3, all b
#pragma unroll
        for (int i = 0; i < 4; ++i) {
            av[i][0] = *(const bf16x8*)(la + baseA + i * 2048 + oh0);
            av[i][1] = *(const bf16x8*)(la + baseA + i * 2048 + oh1);
        }
#pragma unroll
        for (int j = 0; j < 4; ++j) {
            bv[j][0] = *(const bf16x8*)(lb + baseB + j * 2048 + oh0);
            bv[j][1] = *(const bf16x8*)(lb + baseB + j * 2048 + oh1);
        }
        // P1: Q(0,0)
        __builtin_amdgcn_s_setprio(1);
#pragma unroll
        for (int i = 0; i < 4; ++i)
#pragma unroll
            for (int j = 0; j < 2; ++j) {
                acc[i][j] = __builtin_amdgcn_mfma_f32_16x16x32_bf16(av[i][0], bv[j][0], acc[i][j], 0, 0, 0);
                acc[i][j] = __builtin_amdgcn_mfma_f32_16x16x32_bf16(av[i][1], bv[j][1], acc[i][j], 0, 0, 0);
            }
        __builtin_amdgcn_s_setprio(0);
        // P2: Q(0,1)
        __builtin_amdgcn_s_setprio(1);
#pragma unroll
        for (int i = 0; i < 4; ++i)
#pragma unroll
            for (int j = 2; j < 4; ++j) {
                acc[i][j] = __builtin_amdgcn_mfma_f32_16x16x32_bf16(av[i][0], bv[j][0], acc[i][j], 0, 0, 0);
                acc[i][j] = __builtin_amdgcn_mfma_f32_16x16x32_bf16(av[i][1], bv[j][1], acc[i][j], 0, 0, 0);
            }
        __builtin_amdgcn_s_setprio(0);
        // P3 reads: a rows i=4..7, then Q(1,0)
#pragma unroll
        for (int i = 0; i < 4; ++i) {
            av[i][0] = *(const bf16x8*)(la + baseA + (i + 4) * 2048 + oh0);
            av[i][1] = *(const bf16x8*)(la + baseA + (i + 4) * 2048 + oh1);
        }
        __builtin_amdgcn_s_setprio(1);
#pragma unroll
        for (int i = 0; i < 4; ++i)
#pragma unroll
            for (int j = 0; j < 2; ++j) {
                acc[4 + i][j] = __builtin_amdgcn_mfma_f32_16x16x32_bf16(av[i][0], bv[j][0], acc[4 + i][j], 0, 0, 0);
                acc[4 + i][j] = __builtin_amdgcn_mfma_f32_16x16x32_bf16(av[i][1], bv[j][1], acc[4 + i][j], 0, 0, 0);
            }
        __builtin_amdgcn_s_setprio(0);
        // P4: Q(1,1)
        __builtin_amdgcn_s_setprio(1);
#pragma unroll
        for (int i = 0; i < 4; ++i)
#pragma unroll
            for (int j = 2; j < 4; ++j) {
                acc[4 + i][j] = __builtin_amdgcn_mfma_f32_16x16x32_bf16(av[i][0], bv[j][0], acc[4 + i][j], 0, 0, 0);
                acc[4 + i][j] = __builtin_amdgcn_mfma_f32_16x16x32_bf16(av[i][1], bv[j][1], acc[4 + i][j], 0, 0, 0);
            }
        __builtin_amdgcn_s_setprio(0);

        __builtin_amdgcn_s_barrier();   // all reads of buf[cur] done
    }
#undef STAGE

    // --- epilogue: bias (+Ux), 10-step fixed point, stores ---
#pragma unroll
    for (int i = 0; i < 8; ++i) {
#pragma unroll
        for (int j = 0; j < 4; ++j) {
            const int col = n0 + wc * 64 + j * 16 + lr;
            const float bvv = bias[col];
            float c[4], sv[4];
#pragma unroll
            for (int jj = 0; jj < 4; ++jj) {
                const int row = m0 + wr * 128 + i * 16 + q * 4 + jj;
                c[jj] = acc[i][j][jj] + bvv;
                if (PHASE == 1) {
                    if (n0 < 1024) c[jj] += Ux[(size_t)row * H1W + col];
                }
                sv[jj] = s_in[(size_t)row * 4096 + col];
            }
#pragma unroll 1
            for (int t = 0; t < NSTEP; ++t) {
#pragma unroll
                for (int jj = 0; jj < 4; ++jj) {
                    float r  = rho_f(sv[jj]);
                    float rd = 4.0f * r * (1.0f - r);
                    sv[jj] = 0.5f * sv[jj] + 0.5f * rd * c[jj];
                }
            }
#pragma unroll
            for (int jj = 0; jj < 4; ++jj) {
                const int row = m0 + wr * 128 + i * 16 + q * 4 + jj;
                out[(size_t)row * 4096 + col] = sv[jj];
                if (PHASE == 1) {
                    float r = rho_f(sv[jj]);
                    u16 h, l; split2(r, h, l);
                    R2hi[(size_t)row * SEW + col] = h;
                    R2lo[(size_t)row * SEW + col] = l;
                }
            }
        }
    }
}

// ---------------------------------------------------------------------------
extern "C" void kernel_launch(void* const* d_in, const int* in_sizes, int n_in,
                              void* d_out, int out_size, void* d_ws, size_t ws_size,
                              hipStream_t stream) {
    (void)in_sizes; (void)n_in; (void)out_size; (void)ws_size;
    const float* Ux     = (const float*)d_in[0];
    const float* s      = (const float*)d_in[1];
    const float* W      = (const float*)d_in[2];
    const float* b_even = (const float*)d_in[3];
    const float* b_odd  = (const float*)d_in[4];
    float* out = (float*)d_out;

    char* ws = (char*)d_ws;
    const size_t MB = 1024ull * 1024ull;
    // workspace layout (288 MB total)
    u16* R1hi = (u16*)(ws);              // 64 MB  rho(s_even) hi
    u16* R1lo = (u16*)(ws + 64 * MB);    // 64 MB  rho(s_even) lo
    u16* R2hi = (u16*)(ws + 128 * MB);   // 64 MB  rho(s_odd)  hi
    u16* R2lo = (u16*)(ws + 192 * MB);   // 64 MB  rho(s_odd)  lo
    u16* Whi  = (u16*)(ws + 256 * MB);   // 8 MB
    u16* Wlo  = (u16*)(ws + 264 * MB);   // 8 MB
    u16* WThi = (u16*)(ws + 272 * MB);   // 8 MB
    u16* WTlo = (u16*)(ws + 280 * MB);   // 8 MB

    prep_w<<<dim3(64, 64), dim3(32, 8), 0, stream>>>(W, Whi, Wlo, WThi, WTlo);
    prep_rho<<<(BATCH * SEW / 4) / 256, 256, 0, stream>>>(s, R1hi, R1lo);

    // Phase 1: C_odd = rho(s_even) @ W  (BT = WT arrays); iterate s_odd
    gemm_fused<1><<<dim3(512), 512, 0, stream>>>(
        R1hi, R1lo, WThi, WTlo, b_odd, Ux,
        s + SEW, out + SEW, R2hi, R2lo);

    // Phase 2: C_even = rho(s_odd) @ W.T (BT = W arrays); iterate s_even
    gemm_fused<2><<<dim3(512), 512, 0, stream>>>(
        R2hi, R2lo, Whi, Wlo, b_even, nullptr,
        s, out, nullptr, nullptr);
}

// Round 10
// 1555.936 us; speedup vs baseline: 1.0321x; 1.0321x over previous
//
#include <hip/hip_runtime.h>
#include <hip/hip_bf16.h>

// Problem constants
#define BATCH 16384
#define SEW   2048      // SE == SO == 2048
#define H1W   1024
#define NSTEP 10

typedef unsigned short u16;
typedef __attribute__((ext_vector_type(8))) __bf16 bf16x8;
typedef __attribute__((ext_vector_type(4))) float   f32x4;

// Split fp32 into bf16 hi + bf16 lo (truncation; x == hi + lo + O(2^-16 |x|))
__device__ __forceinline__ void split2(float x, u16& h, u16& l) {
    unsigned u = __float_as_uint(x);
    h = (u16)(u >> 16);
    float hf = __uint_as_float(u & 0xFFFF0000u);
    float r  = x - hf;                       // exact (mantissa suffix)
    l = (u16)(__float_as_uint(r) >> 16);
}

__device__ __forceinline__ float rho_f(float x) {
    return 1.0f / (1.0f + __expf(2.0f - 4.0f * x));
}

// 16-byte async global->LDS copy
__device__ __forceinline__ void gl2lds16(const u16* g, u16* l) {
    __builtin_amdgcn_global_load_lds(
        (const __attribute__((address_space(1))) void*)g,
        (__attribute__((address_space(3))) void*)l, 16, 0, 0);
}

// ---------------------------------------------------------------------------
// prep_w: W (2048x2048 f32) -> Whi/Wlo and transposed WThi/WTlo (bf16 halves)
// ---------------------------------------------------------------------------
__global__ void prep_w(const float* __restrict__ W,
                       u16* __restrict__ Whi, u16* __restrict__ Wlo,
                       u16* __restrict__ WThi, u16* __restrict__ WTlo) {
    __shared__ float tile[32][33];
    const int tx = threadIdx.x, ty = threadIdx.y;
    const int x = blockIdx.x * 32 + tx;
#pragma unroll
    for (int k = 0; k < 4; ++k) {
        int y = blockIdx.y * 32 + ty + k * 8;
        float v = W[y * SEW + x];
        tile[ty + k * 8][tx] = v;
        u16 h, l; split2(v, h, l);
        Whi[y * SEW + x] = h; Wlo[y * SEW + x] = l;
    }
    __syncthreads();
#pragma unroll
    for (int k = 0; k < 4; ++k) {
        int r = blockIdx.x * 32 + ty + k * 8;   // WT row (= W col)
        int c = blockIdx.y * 32 + tx;           // WT col (= W row)
        float v = tile[tx][ty + k * 8];         // = W[c][r]
        u16 h, l; split2(v, h, l);
        WThi[r * SEW + c] = h; WTlo[r * SEW + c] = l;
    }
}

// ---------------------------------------------------------------------------
// prep_rho: R1 = rho(s_even) split to bf16 hi/lo.  s row stride 4096.
// ---------------------------------------------------------------------------
__global__ void prep_rho(const float* __restrict__ s,
                         u16* __restrict__ Rhi, u16* __restrict__ Rlo) {
    int i = blockIdx.x * blockDim.x + threadIdx.x;   // 0 .. B*SE/4-1
    int e = i << 2;
    int row = e >> 11;
    int col = e & 2047;
    const float4 v = *(const float4*)(s + ((size_t)row << 12) + col);
    float xs[4] = {v.x, v.y, v.z, v.w};
    u16 h[4], l[4];
#pragma unroll
    for (int k = 0; k < 4; ++k) {
        float r = rho_f(xs[k]);
        split2(r, h[k], l[k]);
    }
    *(ushort4*)(Rhi + e) = make_ushort4(h[0], h[1], h[2], h[3]);
    *(ushort4*)(Rlo + e) = make_ushort4(l[0], l[1], l[2], l[3]);
}

// ---------------------------------------------------------------------------
// Split-bf16 GEMM, TLP-first structure.
//  BM=BN=128, BK=32, 256 threads = 4 waves (2x2), 64x64 out per wave.
//  ~3 blocks/CU co-resident (32KB LDS, launch_bounds(256,3)) -> cross-block
//  overlap hides staging latency (m114), unlike the failed 1-block/CU 256^2.
//  Virtual-K: per 32-wide K-tile, 3 virtual terms pick staged sources:
//    t=0: Ahi*Bhi   t=1: Ahi*Blo   t=2: Alo*Bhi
//  Double-buffered LDS ring, counted s_waitcnt vmcnt(4) (never 0 in loop),
//  raw s_barrier, XOR-swizzled reads via pre-swizzled global source cols.
// ---------------------------------------------------------------------------
template <int PHASE>
__global__ __launch_bounds__(256, 3)
void gemm_fused(const u16* __restrict__ Ahi, const u16* __restrict__ Alo,
                const u16* __restrict__ Bhi, const u16* __restrict__ Blo,
                const float* __restrict__ bias,
                const float* __restrict__ Ux,
                const float* __restrict__ s_in,   // pre-offset, row stride 4096
                float* __restrict__ out,          // pre-offset, row stride 4096
                u16* __restrict__ R2hi, u16* __restrict__ R2lo) {
    __shared__ u16 ldsA[2][128 * 32];   // 2 x 8KB
    __shared__ u16 ldsB[2][128 * 32];   // 2 x 8KB

    const int tid = threadIdx.x;

    // ---- bijective XCD swizzle: 2048 wgs, hw xcd = wgid & 7.
    // XCD0 gets L=0..255: m-panels 0..15 with all 16 n-blocks each ->
    // A-panel reuse stays on one XCD's L2.
    const int wg = blockIdx.x;
    const int L  = (wg & 7) * 256 + (wg >> 3);
    const int m0 = (L >> 4) * 128;
    const int n0 = (L & 15) * 128;

    // ---- k range from block sparsity (units of 32-wide k-tiles)
    int kt0, nkt;
    if (PHASE == 1) { kt0 = 0;                    nkt = (n0 < 1024) ? 32 : 64; }
    else            { kt0 = (n0 < 1024) ? 0 : 32; nkt = (n0 < 1024) ? 64 : 32; }
    const int nvt = 3 * nkt;

    // ---- staging: 512 16B chunks per 128x32 tile, 2 per thread (c=tid, tid+256)
    // chunk c: row = c>>2 (tid>>2, +64 for chunk1), slot = tid&3.
    // LDS dest linear; global source k-chunk pre-swizzled by the read-side XOR
    // so read(swz) o stage(swz) = identity.
    const int srow = tid >> 2;
    const int sswz = (tid >> 3) & 3;               // (row>>1)&3, same both chunks
    const int scol = ((tid & 3) ^ sswz) * 8;       // element offset in 32-k row
    const int aoff0 = (m0 + srow) * SEW + scol;
    const int boff0 = (n0 + srow) * SEW + scol;

    // ---- fragment read offsets (bytes), swizzled. Row = 64B (4 slots of 16B);
    // slot' = q ^ ((row>>1)&3) spreads 16 lanes over 8 bank-groups -> 2-way
    // aliasing only (free). Same formula R1 measured at 0 conflicts.
    const int lane = tid & 63;
    const int w  = tid >> 6;
    const int wr = w >> 1, wc = w & 1;             // 2x2 wave grid
    const int lr = lane & 15, q = lane >> 4;
    const int oh = ((q ^ ((lr >> 1) & 3))) << 4;   // byte slot within row
    int offA[4], offB[4];
#pragma unroll
    for (int i = 0; i < 4; ++i) {
        offA[i] = (wr * 64 + i * 16 + lr) * 64 + oh;
        offB[i] = (wc * 64 + i * 16 + lr) * 64 + oh;
    }

    f32x4 acc[4][4];
    const f32x4 zero = {0.f, 0.f, 0.f, 0.f};
#pragma unroll
    for (int i = 0; i < 4; ++i)
#pragma unroll
        for (int j = 0; j < 4; ++j) acc[i][j] = zero;

#define STAGE(As, Bs, kk, buf) do {                                          \
        u16* dA_ = &ldsA[buf][tid * 8];                                      \
        u16* dB_ = &ldsB[buf][tid * 8];                                      \
        const u16* sa_ = (As) + aoff0 + (kk);                                \
        const u16* sb_ = (Bs) + boff0 + (kk);                                \
        gl2lds16(sa_, dA_);                                                  \
        gl2lds16(sa_ + 64 * SEW, dA_ + 2048);                                \
        gl2lds16(sb_, dB_);                                                  \
        gl2lds16(sb_ + 64 * SEW, dB_ + 2048);                                \
    } while (0)

    // prologue: stage vt=0 (t=0: Ahi*Bhi)
    int skk = kt0 * 32;
    int st  = 1;                 // term of the NEXT tile to stage
    STAGE(Ahi, Bhi, skk, 0);

    for (int vt = 0; vt < nvt; ++vt) {
        const int cur = vt & 1;
        if (vt + 1 < nvt) {
            const u16* As = (st < 2)  ? Ahi : Alo;
            const u16* Bs = (st == 1) ? Blo : Bhi;
            STAGE(As, Bs, skk, cur ^ 1);            // 4 loads in flight
            if (++st == 3) { st = 0; skk += 32; }
            asm volatile("s_waitcnt vmcnt(4)" ::: "memory");  // tile vt ready
        } else {
            asm volatile("s_waitcnt vmcnt(0)" ::: "memory");
        }
        __builtin_amdgcn_s_barrier();   // buf[cur] published to all waves

        const char* la = (const char*)ldsA[cur];
        const char* lb = (const char*)ldsB[cur];
        bf16x8 av[4], bv[4];
#pragma unroll
        for (int i = 0; i < 4; ++i) av[i] = *(const bf16x8*)(la + offA[i]);
#pragma unroll
        for (int j = 0; j < 4; ++j) bv[j] = *(const bf16x8*)(lb + offB[j]);

        __builtin_amdgcn_s_setprio(1);
#pragma unroll
        for (int i = 0; i < 4; ++i)
#pragma unroll
            for (int j = 0; j < 4; ++j)
                acc[i][j] = __builtin_amdgcn_mfma_f32_16x16x32_bf16(av[i], bv[j], acc[i][j], 0, 0, 0);
        __builtin_amdgcn_s_setprio(0);

        __builtin_amdgcn_s_barrier();   // all reads of buf[cur] done
    }
#undef STAGE

    // --- epilogue: bias (+Ux), 10-step fixed point, stores (R1-proven) ---
#pragma unroll
    for (int i = 0; i < 4; ++i) {
#pragma unroll
        for (int j = 0; j < 4; ++j) {
            const int col = n0 + wc * 64 + j * 16 + lr;
            const float bvv = bias[col];
            float c[4], sv[4];
#pragma unroll
            for (int jj = 0; jj < 4; ++jj) {
                const int row = m0 + wr * 64 + i * 16 + q * 4 + jj;
                c[jj] = acc[i][j][jj] + bvv;
                if (PHASE == 1) {
                    if (n0 < 1024) c[jj] += Ux[(size_t)row * H1W + col];
                }
                sv[jj] = s_in[(size_t)row * 4096 + col];
            }
#pragma unroll 1
            for (int t = 0; t < NSTEP; ++t) {
#pragma unroll
                for (int jj = 0; jj < 4; ++jj) {
                    float r  = rho_f(sv[jj]);
                    float rd = 4.0f * r * (1.0f - r);
                    sv[jj] = 0.5f * sv[jj] + 0.5f * rd * c[jj];
                }
            }
#pragma unroll
            for (int jj = 0; jj < 4; ++jj) {
                const int row = m0 + wr * 64 + i * 16 + q * 4 + jj;
                out[(size_t)row * 4096 + col] = sv[jj];
                if (PHASE == 1) {
                    float r = rho_f(sv[jj]);
                    u16 h, l; split2(r, h, l);
                    R2hi[(size_t)row * SEW + col] = h;
                    R2lo[(size_t)row * SEW + col] = l;
                }
            }
        }
    }
}

// ---------------------------------------------------------------------------
extern "C" void kernel_launch(void* const* d_in, const int* in_sizes, int n_in,
                              void* d_out, int out_size, void* d_ws, size_t ws_size,
                              hipStream_t stream) {
    (void)in_sizes; (void)n_in; (void)out_size; (void)ws_size;
    const float* Ux     = (const float*)d_in[0];
    const float* s      = (const float*)d_in[1];
    const float* W      = (const float*)d_in[2];
    const float* b_even = (const float*)d_in[3];
    const float* b_odd  = (const float*)d_in[4];
    float* out = (float*)d_out;

    char* ws = (char*)d_ws;
    const size_t MB = 1024ull * 1024ull;
    // workspace layout (288 MB total)
    u16* R1hi = (u16*)(ws);              // 64 MB  rho(s_even) hi
    u16* R1lo = (u16*)(ws + 64 * MB);    // 64 MB  rho(s_even) lo
    u16* R2hi = (u16*)(ws + 128 * MB);   // 64 MB  rho(s_odd)  hi
    u16* R2lo = (u16*)(ws + 192 * MB);   // 64 MB  rho(s_odd)  lo
    u16* Whi  = (u16*)(ws + 256 * MB);   // 8 MB
    u16* Wlo  = (u16*)(ws + 264 * MB);   // 8 MB
    u16* WThi = (u16*)(ws + 272 * MB);   // 8 MB
    u16* WTlo = (u16*)(ws + 280 * MB);   // 8 MB

    prep_w<<<dim3(64, 64), dim3(32, 8), 0, stream>>>(W, Whi, Wlo, WThi, WTlo);
    prep_rho<<<(BATCH * SEW / 4) / 256, 256, 0, stream>>>(s, R1hi, R1lo);

    // Phase 1: C_odd = rho(s_even) @ W  (BT = WT arrays); iterate s_odd
    gemm_fused<1><<<dim3(2048), 256, 0, stream>>>(
        R1hi, R1lo, WThi, WTlo, b_odd, Ux,
        s + SEW, out + SEW, R2hi, R2lo);

    // Phase 2: C_even = rho(s_odd) @ W.T (BT = W arrays); iterate s_even
    gemm_fused<2><<<dim3(2048), 256, 0, stream>>>(
        R2hi, R2lo, Whi, Wlo, b_even, nullptr,
        s, out, nullptr, nullptr);
}

// Round 11
// 1520.905 us; speedup vs baseline: 1.0558x; 1.0230x over previous
//
#include <hip/hip_runtime.h>
#include <hip/hip_bf16.h>

// Problem constants
#define BATCH 16384
#define SEW   2048      // SE == SO == 2048
#define H1W   1024
#define NSTEP 10

typedef unsigned short u16;
typedef __attribute__((ext_vector_type(8))) __bf16 bf16x8;
typedef __attribute__((ext_vector_type(4))) float   f32x4;

// Split fp32 into bf16 hi + bf16 lo (truncation; x == hi + lo + O(2^-16 |x|))
__device__ __forceinline__ void split2(float x, u16& h, u16& l) {
    unsigned u = __float_as_uint(x);
    h = (u16)(u >> 16);
    float hf = __uint_as_float(u & 0xFFFF0000u);
    float r  = x - hf;                       // exact (mantissa suffix)
    l = (u16)(__float_as_uint(r) >> 16);
}

__device__ __forceinline__ float rho_f(float x) {
    return 1.0f / (1.0f + __expf(2.0f - 4.0f * x));
}

// 16-byte async global->LDS copy
__device__ __forceinline__ void gl2lds16(const u16* g, u16* l) {
    __builtin_amdgcn_global_load_lds(
        (const __attribute__((address_space(1))) void*)g,
        (__attribute__((address_space(3))) void*)l, 16, 0, 0);
}

// ---------------------------------------------------------------------------
// prep_w: W (2048x2048 f32) -> Whi/Wlo and transposed WThi/WTlo (bf16 halves)
// ---------------------------------------------------------------------------
__global__ void prep_w(const float* __restrict__ W,
                       u16* __restrict__ Whi, u16* __restrict__ Wlo,
                       u16* __restrict__ WThi, u16* __restrict__ WTlo) {
    __shared__ float tile[32][33];
    const int tx = threadIdx.x, ty = threadIdx.y;
    const int x = blockIdx.x * 32 + tx;
#pragma unroll
    for (int k = 0; k < 4; ++k) {
        int y = blockIdx.y * 32 + ty + k * 8;
        float v = W[y * SEW + x];
        tile[ty + k * 8][tx] = v;
        u16 h, l; split2(v, h, l);
        Whi[y * SEW + x] = h; Wlo[y * SEW + x] = l;
    }
    __syncthreads();
#pragma unroll
    for (int k = 0; k < 4; ++k) {
        int r = blockIdx.x * 32 + ty + k * 8;   // WT row (= W col)
        int c = blockIdx.y * 32 + tx;           // WT col (= W row)
        float v = tile[tx][ty + k * 8];         // = W[c][r]
        u16 h, l; split2(v, h, l);
        WThi[r * SEW + c] = h; WTlo[r * SEW + c] = l;
    }
}

// ---------------------------------------------------------------------------
// prep_rho: R1 = rho(s_even) split to bf16 hi/lo.  s row stride 4096.
// ---------------------------------------------------------------------------
__global__ void prep_rho(const float* __restrict__ s,
                         u16* __restrict__ Rhi, u16* __restrict__ Rlo) {
    int i = blockIdx.x * blockDim.x + threadIdx.x;   // 0 .. B*SE/4-1
    int e = i << 2;
    int row = e >> 11;
    int col = e & 2047;
    const float4 v = *(const float4*)(s + ((size_t)row << 12) + col);
    float xs[4] = {v.x, v.y, v.z, v.w};
    u16 h[4], l[4];
#pragma unroll
    for (int k = 0; k < 4; ++k) {
        float r = rho_f(xs[k]);
        split2(r, h[k], l[k]);
    }
    *(ushort4*)(Rhi + e) = make_ushort4(h[0], h[1], h[2], h[3]);
    *(ushort4*)(Rlo + e) = make_ushort4(l[0], l[1], l[2], l[3]);
}

// ---------------------------------------------------------------------------
// Split-bf16 GEMM: stage-once, compute-3-terms.
//  BM=BN=128, BK=32, 256 threads = 4 waves (2x2), 64x64 out per wave.
//  Per k-tile: stage Ah,Al,Bh,Bl ONCE (32KB, 8 gl2lds/thread, fixed pointers)
//  then 48 MFMA/wave: t0 Ah*Bh + t1 Ah*Bl + t2 Al*Bh.  3x the compute cover
//  per prefetch slot vs R10 (whose 16-MFMA rounds couldn't hide L2/L3 latency).
//  Double-buffered LDS ring (64KB -> 2 blocks/CU), counted s_waitcnt vmcnt(8)
//  (never 0 in loop), raw s_barrier, XOR-swizzled reads via pre-swizzled
//  global source columns (measured 0 bank conflicts).
// ---------------------------------------------------------------------------
template <int PHASE>
__global__ __launch_bounds__(256, 2)
void gemm_fused(const u16* __restrict__ Ahi, const u16* __restrict__ Alo,
                const u16* __restrict__ Bhi, const u16* __restrict__ Blo,
                const float* __restrict__ bias,
                const float* __restrict__ Ux,
                const float* __restrict__ s_in,   // pre-offset, row stride 4096
                float* __restrict__ out,          // pre-offset, row stride 4096
                u16* __restrict__ R2hi, u16* __restrict__ R2lo) {
    __shared__ u16 lsAh[2][128 * 32];   // 2 x 8KB each array
    __shared__ u16 lsAl[2][128 * 32];
    __shared__ u16 lsBh[2][128 * 32];
    __shared__ u16 lsBl[2][128 * 32];

    const int tid = threadIdx.x;

    // ---- bijective XCD swizzle: 2048 wgs, hw xcd = wgid & 7.
    const int wg = blockIdx.x;
    const int L  = (wg & 7) * 256 + (wg >> 3);
    const int m0 = (L >> 4) * 128;
    const int n0 = (L & 15) * 128;

    // ---- k range from block sparsity (units of 32-wide k-tiles)
    int kt0, nkt;
    if (PHASE == 1) { kt0 = 0;                    nkt = (n0 < 1024) ? 32 : 64; }
    else            { kt0 = (n0 < 1024) ? 0 : 32; nkt = (n0 < 1024) ? 64 : 32; }

    // ---- staging: 512 16B chunks per 128x32 tile, 2 per thread (c=tid, tid+256)
    // LDS dest linear; global source k-chunk pre-swizzled by the read-side XOR.
    const int srow = tid >> 2;
    const int sswz = (tid >> 3) & 3;               // (row>>1)&3, same both chunks
    const int scol = ((tid & 3) ^ sswz) * 8;       // element offset in 32-k row
    const int aoff0 = (m0 + srow) * SEW + scol;
    const int boff0 = (n0 + srow) * SEW + scol;

    // ---- fragment read offsets (bytes), swizzled (R10-measured: 0 conflicts)
    const int lane = tid & 63;
    const int w  = tid >> 6;
    const int wr = w >> 1, wc = w & 1;             // 2x2 wave grid
    const int lr = lane & 15, q = lane >> 4;
    const int oh = ((q ^ ((lr >> 1) & 3))) << 4;   // byte slot within row
    int offA[4], offB[4];
#pragma unroll
    for (int i = 0; i < 4; ++i) {
        offA[i] = (wr * 64 + i * 16 + lr) * 64 + oh;
        offB[i] = (wc * 64 + i * 16 + lr) * 64 + oh;
    }

    f32x4 acc[4][4];
    const f32x4 zero = {0.f, 0.f, 0.f, 0.f};
#pragma unroll
    for (int i = 0; i < 4; ++i)
#pragma unroll
        for (int j = 0; j < 4; ++j) acc[i][j] = zero;

    // stage all four operand tiles for k-chunk kk into ring slot buf
#define STAGE(kk, buf) do {                                                  \
        const int d0_ = tid * 8;                                             \
        const u16* sa_ = Ahi + aoff0 + (kk);                                 \
        const u16* sb_ = Bhi + boff0 + (kk);                                 \
        const u16* sc_ = Alo + aoff0 + (kk);                                 \
        const u16* sd_ = Blo + boff0 + (kk);                                 \
        gl2lds16(sa_,            &lsAh[buf][d0_]);                           \
        gl2lds16(sa_ + 64 * SEW, &lsAh[buf][d0_ + 2048]);                    \
        gl2lds16(sb_,            &lsBh[buf][d0_]);                           \
        gl2lds16(sb_ + 64 * SEW, &lsBh[buf][d0_ + 2048]);                    \
        gl2lds16(sc_,            &lsAl[buf][d0_]);                           \
        gl2lds16(sc_ + 64 * SEW, &lsAl[buf][d0_ + 2048]);                    \
        gl2lds16(sd_,            &lsBl[buf][d0_]);                           \
        gl2lds16(sd_ + 64 * SEW, &lsBl[buf][d0_ + 2048]);                    \
    } while (0)

    // prologue: stage k-tile 0 into slot 0 (8 loads in flight)
    int kk = kt0 * 32;
    STAGE(kk, 0);

    for (int kt = 0; kt < nkt; ++kt) {
        const int cur = kt & 1;
        if (kt + 1 < nkt) {
            STAGE(kk + 32, cur ^ 1);                           // 16 in flight
            asm volatile("s_waitcnt vmcnt(8)" ::: "memory");   // tile kt ready
        } else {
            asm volatile("s_waitcnt vmcnt(0)" ::: "memory");
        }
        __builtin_amdgcn_s_barrier();   // slot cur published to all waves

        const char* pah = (const char*)lsAh[cur];
        const char* pal = (const char*)lsAl[cur];
        const char* pbh = (const char*)lsBh[cur];
        const char* pbl = (const char*)lsBl[cur];
        bf16x8 ah[4], al[4], bh[4], bl[4];
#pragma unroll
        for (int i = 0; i < 4; ++i) {
            ah[i] = *(const bf16x8*)(pah + offA[i]);
            bh[i] = *(const bf16x8*)(pbh + offB[i]);
        }
#pragma unroll
        for (int i = 0; i < 4; ++i) {
            al[i] = *(const bf16x8*)(pal + offA[i]);
            bl[i] = *(const bf16x8*)(pbl + offB[i]);
        }

        // t0: Ah*Bh
        __builtin_amdgcn_s_setprio(1);
#pragma unroll
        for (int i = 0; i < 4; ++i)
#pragma unroll
            for (int j = 0; j < 4; ++j)
                acc[i][j] = __builtin_amdgcn_mfma_f32_16x16x32_bf16(ah[i], bh[j], acc[i][j], 0, 0, 0);
        __builtin_amdgcn_s_setprio(0);
        // t1: Ah*Bl
        __builtin_amdgcn_s_setprio(1);
#pragma unroll
        for (int i = 0; i < 4; ++i)
#pragma unroll
            for (int j = 0; j < 4; ++j)
                acc[i][j] = __builtin_amdgcn_mfma_f32_16x16x32_bf16(ah[i], bl[j], acc[i][j], 0, 0, 0);
        __builtin_amdgcn_s_setprio(0);
        // t2: Al*Bh
        __builtin_amdgcn_s_setprio(1);
#pragma unroll
        for (int i = 0; i < 4; ++i)
#pragma unroll
            for (int j = 0; j < 4; ++j)
                acc[i][j] = __builtin_amdgcn_mfma_f32_16x16x32_bf16(al[i], bh[j], acc[i][j], 0, 0, 0);
        __builtin_amdgcn_s_setprio(0);

        __builtin_amdgcn_s_barrier();   // all reads of slot cur done
        kk += 32;
    }
#undef STAGE

    // --- epilogue: bias (+Ux), 10-step fixed point, stores (R1-proven) ---
#pragma unroll
    for (int i = 0; i < 4; ++i) {
#pragma unroll
        for (int j = 0; j < 4; ++j) {
            const int col = n0 + wc * 64 + j * 16 + lr;
            const float bvv = bias[col];
            float c[4], sv[4];
#pragma unroll
            for (int jj = 0; jj < 4; ++jj) {
                const int row = m0 + wr * 64 + i * 16 + q * 4 + jj;
                c[jj] = acc[i][j][jj] + bvv;
                if (PHASE == 1) {
                    if (n0 < 1024) c[jj] += Ux[(size_t)row * H1W + col];
                }
                sv[jj] = s_in[(size_t)row * 4096 + col];
            }
#pragma unroll 1
            for (int t = 0; t < NSTEP; ++t) {
#pragma unroll
                for (int jj = 0; jj < 4; ++jj) {
                    float r  = rho_f(sv[jj]);
                    float rd = 4.0f * r * (1.0f - r);
                    sv[jj] = 0.5f * sv[jj] + 0.5f * rd * c[jj];
                }
            }
#pragma unroll
            for (int jj = 0; jj < 4; ++jj) {
                const int row = m0 + wr * 64 + i * 16 + q * 4 + jj;
                out[(size_t)row * 4096 + col] = sv[jj];
                if (PHASE == 1) {
                    float r = rho_f(sv[jj]);
                    u16 h, l; split2(r, h, l);
                    R2hi[(size_t)row * SEW + col] = h;
                    R2lo[(size_t)row * SEW + col] = l;
                }
            }
        }
    }
}

// ---------------------------------------------------------------------------
extern "C" void kernel_launch(void* const* d_in, const int* in_sizes, int n_in,
                              void* d_out, int out_size, void* d_ws, size_t ws_size,
                              hipStream_t stream) {
    (void)in_sizes; (void)n_in; (void)out_size; (void)ws_size;
    const float* Ux     = (const float*)d_in[0];
    const float* s      = (const float*)d_in[1];
    const float* W      = (const float*)d_in[2];
    const float* b_even = (const float*)d_in[3];
    const float* b_odd  = (const float*)d_in[4];
    float* out = (float*)d_out;

    char* ws = (char*)d_ws;
    const size_t MB = 1024ull * 1024ull;
    // workspace layout (288 MB total)
    u16* R1hi = (u16*)(ws);              // 64 MB  rho(s_even) hi
    u16* R1lo = (u16*)(ws + 64 * MB);    // 64 MB  rho(s_even) lo
    u16* R2hi = (u16*)(ws + 128 * MB);   // 64 MB  rho(s_odd)  hi
    u16* R2lo = (u16*)(ws + 192 * MB);   // 64 MB  rho(s_odd)  lo
    u16* Whi  = (u16*)(ws + 256 * MB);   // 8 MB
    u16* Wlo  = (u16*)(ws + 264 * MB);   // 8 MB
    u16* WThi = (u16*)(ws + 272 * MB);   // 8 MB
    u16* WTlo = (u16*)(ws + 280 * MB);   // 8 MB

    prep_w<<<dim3(64, 64), dim3(32, 8), 0, stream>>>(W, Whi, Wlo, WThi, WTlo);
    prep_rho<<<(BATCH * SEW / 4) / 256, 256, 0, stream>>>(s, R1hi, R1lo);

    // Phase 1: C_odd = rho(s_even) @ W  (BT = WT arrays); iterate s_odd
    gemm_fused<1><<<dim3(2048), 256, 0, stream>>>(
        R1hi, R1lo, WThi, WTlo, b_odd, Ux,
        s + SEW, out + SEW, R2hi, R2lo);

    // Phase 2: C_even = rho(s_odd) @ W.T (BT = W arrays); iterate s_even
    gemm_fused<2><<<dim3(2048), 256, 0, stream>>>(
        R2hi, R2lo, Whi, Wlo, b_even, nullptr,
        s, out, nullptr, nullptr);
}